// Round 1
// baseline (3473.811 us; speedup 1.0000x reference)
//
#include <hip/hip_runtime.h>
#include <math.h>

#define N_USERS 100000
#define M_ITEMS 50000
#define N_NODES 150000
#define DIM 64
#define N_CATS 1000
#define TIME_BINS 24
#define NNZ_CNT 4800000
#define BATCH 1024
#define NE (N_NODES * DIM)          // 9,600,000 floats per embedding buffer
#define TWO_PI 6.283185307179586f

// ---------------------------------------------------------------------------
// init: A = concat(user_emb, item_emb); ACC = A; B = 0
// ---------------------------------------------------------------------------
__global__ __launch_bounds__(256) void init_kernel(
    const float* __restrict__ user_emb, const float* __restrict__ item_emb,
    float* __restrict__ A, float* __restrict__ B, float* __restrict__ ACC) {
  const int n4 = NE / 4;               // 2,400,000 float4s
  const int userEnd4 = (N_USERS * DIM) / 4;  // 1,600,000
  int stride = gridDim.x * blockDim.x;
  for (int i = blockIdx.x * blockDim.x + threadIdx.x; i < n4; i += stride) {
    float4 v;
    if (i < userEnd4) {
      v = ((const float4*)user_emb)[i];
    } else {
      v = ((const float4*)item_emb)[i - userEnd4];
    }
    ((float4*)A)[i] = v;
    ((float4*)ACC)[i] = v;
    ((float4*)B)[i] = make_float4(0.f, 0.f, 0.f, 0.f);
  }
}

// ---------------------------------------------------------------------------
// spmm: enext[row] += val * ecur[col], one wave (64 lanes) per nnz,
// contiguous chunk per wave so index loads stream.
// ---------------------------------------------------------------------------
__global__ __launch_bounds__(256) void spmm_kernel(
    const float* __restrict__ ecur, float* __restrict__ enext,
    const int* __restrict__ rows, const int* __restrict__ cols,
    const float* __restrict__ vals) {
  const int nwaves = gridDim.x * (blockDim.x / 64);
  const int wave = blockIdx.x * (blockDim.x / 64) + (threadIdx.x >> 6);
  const int lane = threadIdx.x & 63;
  const int chunk = (NNZ_CNT + nwaves - 1) / nwaves;
  int start = wave * chunk;
  int end = start + chunk;
  if (end > NNZ_CNT) end = NNZ_CNT;
  for (int nz = start; nz < end; ++nz) {
    int r = rows[nz];
    int c = cols[nz];
    float v = vals[nz];
    float x = ecur[c * DIM + lane];
    atomicAdd(&enext[r * DIM + lane], v * x);
  }
}

// ---------------------------------------------------------------------------
// post: ACC += src; zbuf = 0   (zbuf becomes the next layer's output buffer)
// ---------------------------------------------------------------------------
__global__ __launch_bounds__(256) void post_kernel(
    float* __restrict__ ACC, const float* __restrict__ src,
    float* __restrict__ zbuf) {
  const int n4 = NE / 4;
  int stride = gridDim.x * blockDim.x;
  for (int i = blockIdx.x * blockDim.x + threadIdx.x; i < n4; i += stride) {
    float4 a = ((const float4*)ACC)[i];
    float4 s = ((const float4*)src)[i];
    a.x += s.x; a.y += s.y; a.z += s.z; a.w += s.w;
    ((float4*)ACC)[i] = a;
    ((float4*)zbuf)[i] = make_float4(0.f, 0.f, 0.f, 0.f);
  }
}

// ---------------------------------------------------------------------------
// clock: per user b, compute gaussian-weighted clock vector and write the
// transposed user matrix U2T[128][1024]:
//   U2T[d][b]      = 0.25 * ACC[users[b]*64 + d]        (light user emb)
//   U2T[64+d][b]   = 0.5  * v_clock[b][d]               (ALPHA folded)
// ---------------------------------------------------------------------------
__global__ __launch_bounds__(64) void clock_kernel(
    const int* __restrict__ users, const float* __restrict__ thetas,
    const int* __restrict__ top3, const float* __restrict__ cat_emb,
    const float* __restrict__ ACC, float* __restrict__ U2T) {
  int b = blockIdx.x;
  int d = threadIdx.x;
  int u = users[b];
  float theta = thetas[b];
  float cur = theta * ((float)TIME_BINS / TWO_PI);

  float w[TIME_BINS];
  float S = 0.f;
#pragma unroll
  for (int h = 0; h < TIME_BINS; ++h) {
    float diff = fabsf(cur - (float)h);
    float delta = fminf(diff, (float)TIME_BINS - diff);
    float wh = expf(-0.5f * delta * delta);
    w[h] = wh;
    S += wh;
  }
  float inv = 1.f / (S + 1e-8f);

  float v = 0.f;
#pragma unroll
  for (int h = 0; h < TIME_BINS; ++h) {
    int base = u * (TIME_BINS * 3) + h * 3;
    int i0 = top3[base + 0];
    int i1 = top3[base + 1];
    int i2 = top3[base + 2];
    float he = (cat_emb[i0 * DIM + d] + cat_emb[i1 * DIM + d] +
                cat_emb[i2 * DIM + d]) * (1.f / 3.f);
    v += w[h] * he;
  }
  U2T[d * BATCH + b] = 0.25f * ACC[u * DIM + d];
  U2T[(DIM + d) * BATCH + b] = 0.5f * v * inv;
}

// ---------------------------------------------------------------------------
// build item matrix IT[128][50000]:
//   IT[k][m]    = 0.25 * ACC[(N_USERS+m)*64 + k]   (light item emb)
//   IT[64+k][m] = cat_emb[item_cat_ids[m]*64 + k]
// ---------------------------------------------------------------------------
__global__ __launch_bounds__(64) void build_it_kernel(
    const float* __restrict__ ACC, const float* __restrict__ cat_emb,
    const int* __restrict__ item_cat, float* __restrict__ IT) {
  int m = blockIdx.x * 64 + threadIdx.x;
  if (m >= M_ITEMS) return;
  int cid = item_cat[m];
#pragma unroll 4
  for (int k = 0; k < DIM; ++k) {
    IT[k * M_ITEMS + m] = 0.25f * ACC[(N_USERS + m) * DIM + k];
    IT[(DIM + k) * M_ITEMS + m] = cat_emb[cid * DIM + k];
  }
}

// ---------------------------------------------------------------------------
// gemm: out[b][m] = sum_{k<128} U2T[k][b] * IT[k][m]
// 64x64 tile per block, 256 threads, 4x4 register micro-tile, K chunks of 32.
// ---------------------------------------------------------------------------
#define GK 32
#define LDP 72  // padded LDS row stride (floats), 16B-aligned, conflict-light
__global__ __launch_bounds__(256) void gemm_kernel(
    const float* __restrict__ U2T, const float* __restrict__ IT,
    float* __restrict__ out) {
  __shared__ float sU[GK][LDP];
  __shared__ float sI[GK][LDP];
  const int m0 = blockIdx.x * 64;
  const int b0 = blockIdx.y * 64;
  const int tid = threadIdx.x;
  const int tx = tid & 15;   // item-dim group (4 m each)
  const int ty = tid >> 4;   // batch-dim group (4 b each)
  const bool full = (m0 + 64 <= M_ITEMS);

  float acc[4][4] = {};

  for (int k0 = 0; k0 < 2 * DIM; k0 += GK) {
    // stage 32x64 U-tile and 32x64 I-tile; 8 elements per thread each
    int linear = tid * 8;
    int kk = linear >> 6;
    int col = linear & 63;
    {
      const float* src = &U2T[(k0 + kk) * BATCH + b0 + col];
      float4 v0 = *(const float4*)(src);
      float4 v1 = *(const float4*)(src + 4);
      *(float4*)&sU[kk][col] = v0;
      *(float4*)&sU[kk][col + 4] = v1;
    }
    if (full) {
      const float* src = &IT[(k0 + kk) * M_ITEMS + m0 + col];
      float4 v0 = *(const float4*)(src);
      float4 v1 = *(const float4*)(src + 4);
      *(float4*)&sI[kk][col] = v0;
      *(float4*)&sI[kk][col + 4] = v1;
    } else {
#pragma unroll
      for (int j = 0; j < 8; ++j) {
        int m = m0 + col + j;
        sI[kk][col + j] = (m < M_ITEMS) ? IT[(k0 + kk) * M_ITEMS + m] : 0.f;
      }
    }
    __syncthreads();

#pragma unroll
    for (int k = 0; k < GK; ++k) {
      float4 uv = *(const float4*)&sU[k][ty * 4];
      float4 iv = *(const float4*)&sI[k][tx * 4];
      float ua[4] = {uv.x, uv.y, uv.z, uv.w};
      float ia[4] = {iv.x, iv.y, iv.z, iv.w};
#pragma unroll
      for (int bi = 0; bi < 4; ++bi)
#pragma unroll
        for (int mi = 0; mi < 4; ++mi)
          acc[bi][mi] = fmaf(ua[bi], ia[mi], acc[bi][mi]);
    }
    __syncthreads();
  }

#pragma unroll
  for (int bi = 0; bi < 4; ++bi) {
    int b = b0 + ty * 4 + bi;
    int m = m0 + tx * 4;
    if (full) {
      float4 v = make_float4(acc[bi][0], acc[bi][1], acc[bi][2], acc[bi][3]);
      *(float4*)&out[b * M_ITEMS + m] = v;
    } else {
#pragma unroll
      for (int mi = 0; mi < 4; ++mi)
        if (m + mi < M_ITEMS) out[b * M_ITEMS + m + mi] = acc[bi][mi];
    }
  }
}

// ---------------------------------------------------------------------------
// launch
// ---------------------------------------------------------------------------
extern "C" void kernel_launch(void* const* d_in, const int* in_sizes, int n_in,
                              void* d_out, int out_size, void* d_ws, size_t ws_size,
                              hipStream_t stream) {
  const float* user_emb   = (const float*)d_in[0];
  const float* item_emb   = (const float*)d_in[1];
  const float* cat_emb    = (const float*)d_in[2];
  const float* graph_vals = (const float*)d_in[3];
  const int*   graph_rows = (const int*)d_in[4];
  const int*   graph_cols = (const int*)d_in[5];
  const int*   top3       = (const int*)d_in[6];
  const int*   item_cat   = (const int*)d_in[7];
  const int*   users      = (const int*)d_in[8];
  const float* thetas     = (const float*)d_in[9];
  float* out = (float*)d_out;

  // workspace layout (floats): A | B | ACC | U2T(128x1024) | IT(128x50000)
  float* A   = (float*)d_ws;
  float* B   = A + NE;
  float* ACC = B + NE;
  float* U2T = ACC + NE;
  float* IT  = U2T + 2 * DIM * BATCH;
  // total: 3*9.6M + 131072 + 6.4M floats = ~141.3 MB, must fit ws_size

  init_kernel<<<2048, 256, 0, stream>>>(user_emb, item_emb, A, B, ACC);

  float* cur = A;
  float* nxt = B;
  for (int l = 0; l < 3; ++l) {
    spmm_kernel<<<2048, 256, 0, stream>>>(cur, nxt, graph_rows, graph_cols,
                                          graph_vals);
    post_kernel<<<2048, 256, 0, stream>>>(ACC, nxt, cur);
    float* t = cur; cur = nxt; nxt = t;
  }

  clock_kernel<<<BATCH, 64, 0, stream>>>(users, thetas, top3, cat_emb, ACC, U2T);
  build_it_kernel<<<(M_ITEMS + 63) / 64, 64, 0, stream>>>(ACC, cat_emb,
                                                          item_cat, IT);
  dim3 ggrid((M_ITEMS + 63) / 64, BATCH / 64);
  gemm_kernel<<<ggrid, 256, 0, stream>>>(U2T, IT, out);
}

// Round 2
// 2583.745 us; speedup vs baseline: 1.3445x; 1.3445x over previous
//
#include <hip/hip_runtime.h>
#include <math.h>

#define N_USERS 100000
#define M_ITEMS 50000
#define N_NODES 150000
#define DIM 64
#define TIME_BINS 24
#define NNZ_CNT 4800000
#define BATCH 1024
#define NE (N_NODES * DIM)   // 9,600,000
#define NU (N_USERS * DIM)   // 6,400,000
#define NI (M_ITEMS * DIM)   // 3,200,000
#define TWO_PI 6.283185307179586f

// ---------------------------------------------------------------------------
// init: A = concat(user_emb, item_emb); ACCI = item_emb (layer-0 term)
// ---------------------------------------------------------------------------
__global__ __launch_bounds__(256) void init_kernel(
    const float* __restrict__ user_emb, const float* __restrict__ item_emb,
    float* __restrict__ A, float* __restrict__ ACCI) {
  const int nA4 = NE / 4, nI4 = NI / 4, u4 = NU / 4;
  int stride = gridDim.x * blockDim.x;
  for (int i = blockIdx.x * blockDim.x + threadIdx.x; i < nA4 + nI4; i += stride) {
    if (i < nA4) {
      float4 v = (i < u4) ? ((const float4*)user_emb)[i]
                          : ((const float4*)item_emb)[i - u4];
      ((float4*)A)[i] = v;
    } else {
      ((float4*)ACCI)[i - nA4] = ((const float4*)item_emb)[i - nA4];
    }
  }
}

__global__ __launch_bounds__(256) void zero_kernel(int* __restrict__ p, int n) {
  int stride = gridDim.x * blockDim.x;
  for (int i = blockIdx.x * blockDim.x + threadIdx.x; i < n; i += stride)
    p[i] = 0;
}

// histogram of row indices
__global__ __launch_bounds__(256) void hist_kernel(
    const int* __restrict__ rows, int* __restrict__ cnt) {
  int stride = gridDim.x * blockDim.x;
  for (int i = blockIdx.x * blockDim.x + threadIdx.x; i < NNZ_CNT; i += stride)
    atomicAdd(&cnt[rows[i]], 1);
}

// single-block exclusive scan of cnt[N_NODES] -> rp[N_NODES+1], cursor[N_NODES]
__global__ __launch_bounds__(1024) void scan_kernel(
    const int* __restrict__ cnt, int* __restrict__ rp, int* __restrict__ cursor) {
  __shared__ int part[1024];
  const int t = threadIdx.x;
  const int CH = (N_NODES + 1023) / 1024;  // 147
  int begin = t * CH;
  int endi = begin + CH;
  if (endi > N_NODES) endi = N_NODES;
  int s = 0;
  for (int i = begin; i < endi; ++i) s += cnt[i];
  part[t] = s;
  __syncthreads();
  for (int off = 1; off < 1024; off <<= 1) {
    int x = (t >= off) ? part[t - off] : 0;
    __syncthreads();
    part[t] += x;
    __syncthreads();
  }
  int run = (t == 0) ? 0 : part[t - 1];
  for (int i = begin; i < endi; ++i) {
    rp[i] = run;
    cursor[i] = run;
    run += cnt[i];
  }
  if (t == 1023) rp[N_NODES] = part[1023];
}

// scatter (col,val) pairs into row-bucketed order
__global__ __launch_bounds__(256) void scatter_kernel(
    const int* __restrict__ rows, const int* __restrict__ cols,
    const float* __restrict__ vals, int* __restrict__ cursor,
    int2* __restrict__ pairs) {
  int stride = gridDim.x * blockDim.x;
  for (int i = blockIdx.x * blockDim.x + threadIdx.x; i < NNZ_CNT; i += stride) {
    int r = rows[i];
    int pos = atomicAdd(&cursor[r], 1);
    pairs[pos] = make_int2(cols[i], __float_as_int(vals[i]));
  }
}

// ---------------------------------------------------------------------------
// CSR SpMM: one wave per row, lane = dim. enext[r] = sum v*ecur[c]; item rows
// also accumulate into ACCI. No atomics, no zero-init of enext needed.
// ---------------------------------------------------------------------------
__global__ __launch_bounds__(256) void spmm_csr_kernel(
    const float* __restrict__ ecur, float* __restrict__ enext,
    float* __restrict__ ACCI, const int* __restrict__ rp,
    const int2* __restrict__ pairs) {
  int r = blockIdx.x * 4 + (threadIdx.x >> 6);
  int lane = threadIdx.x & 63;
  if (r >= N_NODES) return;
  int start = rp[r];
  int end = rp[r + 1];
  float acc = 0.f;
  for (int j = start; j < end; ++j) {
    int2 p = pairs[j];                      // wave-uniform 8B broadcast load
    acc = fmaf(__int_as_float(p.y), ecur[p.x * DIM + lane], acc);
  }
  enext[r * DIM + lane] = acc;
  if (r >= N_USERS) {
    int ir = r - N_USERS;
    ACCI[ir * DIM + lane] += acc;
  }
}

// gather batch-user rows of src into UACC (add=0: init, add=1: accumulate)
__global__ __launch_bounds__(256) void uacc_kernel(
    const float* __restrict__ src, const int* __restrict__ users,
    float* __restrict__ UACC, int add) {
  int idx = blockIdx.x * 256 + threadIdx.x;  // BATCH*64 total
  int b = idx >> 6, d = idx & 63;
  int u = users[b];
  float v = src[u * DIM + d];
  if (add) UACC[idx] += v; else UACC[idx] = v;
}

// ---------------------------------------------------------------------------
// clock: U2T[d][b] = 0.25*UACC[b][d]; U2T[64+d][b] = 0.5 * v_clock[b][d]
// ---------------------------------------------------------------------------
__global__ __launch_bounds__(64) void clock_kernel(
    const int* __restrict__ users, const float* __restrict__ thetas,
    const int* __restrict__ top3, const float* __restrict__ cat_emb,
    const float* __restrict__ UACC, float* __restrict__ U2T) {
  int b = blockIdx.x;
  int d = threadIdx.x;
  int u = users[b];
  float cur = thetas[b] * ((float)TIME_BINS / TWO_PI);

  float w[TIME_BINS];
  float S = 0.f;
#pragma unroll
  for (int h = 0; h < TIME_BINS; ++h) {
    float diff = fabsf(cur - (float)h);
    float delta = fminf(diff, (float)TIME_BINS - diff);
    float wh = expf(-0.5f * delta * delta);
    w[h] = wh;
    S += wh;
  }
  float inv = 1.f / (S + 1e-8f);

  float v = 0.f;
#pragma unroll
  for (int h = 0; h < TIME_BINS; ++h) {
    int base = u * (TIME_BINS * 3) + h * 3;
    int i0 = top3[base + 0];
    int i1 = top3[base + 1];
    int i2 = top3[base + 2];
    float he = (cat_emb[i0 * DIM + d] + cat_emb[i1 * DIM + d] +
                cat_emb[i2 * DIM + d]) * (1.f / 3.f);
    v += w[h] * he;
  }
  U2T[d * BATCH + b] = 0.25f * UACC[b * DIM + d];
  U2T[(DIM + d) * BATCH + b] = 0.5f * v * inv;
}

// ---------------------------------------------------------------------------
// build item matrix IT[128][M]: rows 0..63 = 0.25*ACCI^T, 64..127 = cat_emb^T
// ---------------------------------------------------------------------------
__global__ __launch_bounds__(64) void build_it_kernel(
    const float* __restrict__ ACCI, const float* __restrict__ cat_emb,
    const int* __restrict__ item_cat, float* __restrict__ IT) {
  int m = blockIdx.x * 64 + threadIdx.x;
  if (m >= M_ITEMS) return;
  int cid = item_cat[m];
#pragma unroll 4
  for (int k = 0; k < DIM; ++k) {
    IT[k * M_ITEMS + m] = 0.25f * ACCI[m * DIM + k];
    IT[(DIM + k) * M_ITEMS + m] = cat_emb[cid * DIM + k];
  }
}

// ---------------------------------------------------------------------------
// gemm: out[b][m] = sum_{k<128} U2T[k][b] * IT[k][m]
// ---------------------------------------------------------------------------
#define GK 32
#define LDP 72
__global__ __launch_bounds__(256) void gemm_kernel(
    const float* __restrict__ U2T, const float* __restrict__ IT,
    float* __restrict__ out) {
  __shared__ float sU[GK][LDP];
  __shared__ float sI[GK][LDP];
  const int m0 = blockIdx.x * 64;
  const int b0 = blockIdx.y * 64;
  const int tid = threadIdx.x;
  const int tx = tid & 15;
  const int ty = tid >> 4;
  const bool full = (m0 + 64 <= M_ITEMS);

  float acc[4][4] = {};

  for (int k0 = 0; k0 < 2 * DIM; k0 += GK) {
    int linear = tid * 8;
    int kk = linear >> 6;
    int col = linear & 63;
    {
      const float* src = &U2T[(k0 + kk) * BATCH + b0 + col];
      *(float4*)&sU[kk][col] = *(const float4*)(src);
      *(float4*)&sU[kk][col + 4] = *(const float4*)(src + 4);
    }
    if (full) {
      const float* src = &IT[(k0 + kk) * M_ITEMS + m0 + col];
      *(float4*)&sI[kk][col] = *(const float4*)(src);
      *(float4*)&sI[kk][col + 4] = *(const float4*)(src + 4);
    } else {
#pragma unroll
      for (int j = 0; j < 8; ++j) {
        int m = m0 + col + j;
        sI[kk][col + j] = (m < M_ITEMS) ? IT[(k0 + kk) * M_ITEMS + m] : 0.f;
      }
    }
    __syncthreads();

#pragma unroll
    for (int k = 0; k < GK; ++k) {
      float4 uv = *(const float4*)&sU[k][ty * 4];
      float4 iv = *(const float4*)&sI[k][tx * 4];
      float ua[4] = {uv.x, uv.y, uv.z, uv.w};
      float ia[4] = {iv.x, iv.y, iv.z, iv.w};
#pragma unroll
      for (int bi = 0; bi < 4; ++bi)
#pragma unroll
        for (int mi = 0; mi < 4; ++mi)
          acc[bi][mi] = fmaf(ua[bi], ia[mi], acc[bi][mi]);
    }
    __syncthreads();
  }

#pragma unroll
  for (int bi = 0; bi < 4; ++bi) {
    int b = b0 + ty * 4 + bi;
    int m = m0 + tx * 4;
    if (full) {
      float4 v = make_float4(acc[bi][0], acc[bi][1], acc[bi][2], acc[bi][3]);
      *(float4*)&out[b * M_ITEMS + m] = v;
    } else {
#pragma unroll
      for (int mi = 0; mi < 4; ++mi)
        if (m + mi < M_ITEMS) out[b * M_ITEMS + m + mi] = acc[bi][mi];
    }
  }
}

// ---------------------------------------------------------------------------
// launch
// ---------------------------------------------------------------------------
extern "C" void kernel_launch(void* const* d_in, const int* in_sizes, int n_in,
                              void* d_out, int out_size, void* d_ws, size_t ws_size,
                              hipStream_t stream) {
  const float* user_emb   = (const float*)d_in[0];
  const float* item_emb   = (const float*)d_in[1];
  const float* cat_emb    = (const float*)d_in[2];
  const float* graph_vals = (const float*)d_in[3];
  const int*   graph_rows = (const int*)d_in[4];
  const int*   graph_cols = (const int*)d_in[5];
  const int*   top3       = (const int*)d_in[6];
  const int*   item_cat   = (const int*)d_in[7];
  const int*   users      = (const int*)d_in[8];
  const float* thetas     = (const float*)d_in[9];
  float* out = (float*)d_out;

  // workspace layout (4-byte words):
  // A(9.6M) | B(9.6M) | pairs(9.6M) | ACCI(3.2M) | UACC(64K) | cnt | rp | cursor
  float* A      = (float*)d_ws;
  float* B      = A + NE;
  int2*  pairs  = (int2*)(B + NE);
  float* ACCI   = (float*)(pairs + NNZ_CNT);
  float* UACC   = ACCI + NI;
  int*   cnt    = (int*)(UACC + BATCH * DIM);
  int*   rp     = cnt + (N_NODES + 1);
  int*   cursor = rp + (N_NODES + 1);
  // IT / U2T alias A (dead after layer 2)
  float* IT  = A;
  float* U2T = A + 2 * DIM * M_ITEMS;  // 6.4M offset, fits in A's 9.6M

  init_kernel<<<2048, 256, 0, stream>>>(user_emb, item_emb, A, ACCI);
  zero_kernel<<<256, 256, 0, stream>>>(cnt, N_NODES + 1);
  hist_kernel<<<2048, 256, 0, stream>>>(graph_rows, cnt);
  scan_kernel<<<1, 1024, 0, stream>>>(cnt, rp, cursor);
  scatter_kernel<<<2048, 256, 0, stream>>>(graph_rows, graph_cols, graph_vals,
                                           cursor, pairs);
  uacc_kernel<<<BATCH * DIM / 256, 256, 0, stream>>>(user_emb, users, UACC, 0);

  float* cur = A;
  float* nxt = B;
  for (int l = 0; l < 3; ++l) {
    spmm_csr_kernel<<<(N_NODES + 3) / 4, 256, 0, stream>>>(cur, nxt, ACCI, rp,
                                                           pairs);
    uacc_kernel<<<BATCH * DIM / 256, 256, 0, stream>>>(nxt, users, UACC, 1);
    float* t = cur; cur = nxt; nxt = t;
  }

  clock_kernel<<<BATCH, 64, 0, stream>>>(users, thetas, top3, cat_emb, UACC, U2T);
  build_it_kernel<<<(M_ITEMS + 63) / 64, 64, 0, stream>>>(ACCI, cat_emb,
                                                          item_cat, IT);
  dim3 ggrid((M_ITEMS + 63) / 64, BATCH / 64);
  gemm_kernel<<<ggrid, 256, 0, stream>>>(U2T, IT, out);
}